// Round 5
// baseline (390.845 us; speedup 1.0000x reference)
//
#include <hip/hip_runtime.h>
#include <hip/hip_bf16.h>
#include <math.h>

#define H 128
#define K 20
#define EPB 16        // edges per block (M=16 for MFMA)

// ---- workspace layout (float offsets) ----
#define WS_TBL    0            // merged table: 257 rows x 256 floats {W,B}
#define WS_THM    65792        // 256 merged sorted thresholds
#define WS_CNT    66176        // 1 int: M = nP + nN
#define WSB_HI    67072        // 65536 ushort: em_w1 bf16-hi, B-fragment order
#define WSB_LO    99840        // 65536 ushort: em_w1 bf16-lo

typedef __attribute__((ext_vector_type(8))) short short8;
typedef __attribute__((ext_vector_type(4))) float f32x4;

// DPP-based wave64 sum; result valid in lane 63. (used by MLP tail)
template<int CTRL, int RMASK>
__device__ __forceinline__ float dpp_add(float x) {
  int y = __builtin_amdgcn_update_dpp(0, __float_as_int(x), CTRL, RMASK, 0xf, true);
  return x + __int_as_float(y);
}
__device__ __forceinline__ float wave_sum63(float x) {
  x = dpp_add<0xB1,  0xf>(x);
  x = dpp_add<0x4E,  0xf>(x);
  x = dpp_add<0x141, 0xf>(x);
  x = dpp_add<0x140, 0xf>(x);
  x = dpp_add<0x142, 0xa>(x);
  x = dpp_add<0x143, 0xc>(x);
  return x;
}
__device__ __forceinline__ float bcast63(float x) {
  return __int_as_float(__builtin_amdgcn_readlane(__float_as_int(x), 63));
}

// DPP lane-permute mov (full row/bank masks, bound_ctrl=1)
template<int CTRL>
__device__ __forceinline__ float dpp_mov(float x) {
  return __int_as_float(
      __builtin_amdgcn_update_dpp(0, __float_as_int(x), CTRL, 0xf, 0xf, true));
}
template<int L>
__device__ __forceinline__ float rdlane(float x) {
  return __int_as_float(__builtin_amdgcn_readlane(__float_as_int(x), L));
}
// Crossed-select butterfly merge: out[l] = Z_{beta}[l] + Z_{beta}[sigma(l)]
// where Z_0=z0, Z_1=z1 and sigma is the DPP pairing. Requires
// beta(sigma(l)) != beta(l).
template<int CTRL>
__device__ __forceinline__ float merge2(float z0, float z1, bool beta) {
  float keep = beta ? z1 : z0;
  float sel  = beta ? z0 : z1;
  return keep + dpp_mov<CTRL>(sel);
}

__device__ __forceinline__ unsigned short bfbits(float x) {
  __hip_bfloat16 h = __float2bfloat16(x);
  unsigned short u; __builtin_memcpy(&u, &h, 2); return u;
}
__device__ __forceinline__ float bf2f(unsigned short u) {
  return __uint_as_float(((unsigned)u) << 16);
}

// Single fused aux kernel (769 blocks x 128 threads):
//  blocks 0..256  : locally recompute the threshold sort, then build merged-
//                   table row r = blockIdx (block 0 also publishes THM/CNT).
//  blocks 257..768: pack em_w1 into bf16 hi/lo planes, B-fragment order.
__global__ __launch_bounds__(128) void aux_kernel(
    const float* __restrict__ w1v, const float* __restrict__ b1v,
    const float* __restrict__ w2, const float* __restrict__ b2,
    const float* __restrict__ em_w1, float* __restrict__ ws)
{
  int blk = blockIdx.x;
  int tid = threadIdx.x;
  if (blk < 257) {
    __shared__ float th[H];
    __shared__ int grp[H];
    __shared__ int sidx[2 * H];
    __shared__ int Msh;
    float w = w1v[tid], b = b1v[tid];
    int g = (w > 0.f) ? 0 : ((w < 0.f) ? 1 : 2);   // 0=P, 1=N, 2=Z
    float t = (g == 2) ? 0.f : (-b / w);
    th[tid] = t; grp[tid] = g;
    if (tid == 0) Msh = 0;
    __syncthreads();
    if (g != 2) {
      int r = 0;
      for (int i = 0; i < H; i++)
        if (grp[i] != 2 && (th[i] < t || (th[i] == t && i < tid))) r++;
      sidx[r] = (tid << 1) | (g == 0 ? 1 : 0);     // bit0 = isP
      atomicAdd(&Msh, 1);
      if (blk == 0) ws[WS_THM + r] = t;            // publish for main
    }
    __syncthreads();
    int M = Msh;
    if (blk == 0 && tid == 0) ((int*)(ws + WS_CNT))[0] = M;
    int r = blk;
    if (r > M) return;
    int d = tid;
    // BASE[d] = tp_b2[d] + sum over (w1==0, b1>0) of b1*w2[h][d]
    float accW = 0.f, accB = b2[d];
    for (int i = 0; i < H; i++)
      if (grp[i] == 2 && b1v[i] > 0.f) accB += b1v[i] * w2[i * H + d];
    #pragma unroll 4
    for (int i = 0; i < M; i++) {
      int ent = sidx[i];
      int h = ent >> 1;
      int isP = ent & 1;
      int take = (i < r) ? isP : (1 - isP);
      if (take) {
        float wv = w2[h * H + d];
        accW += w1v[h] * wv;
        accB += b1v[h] * wv;
      }
    }
    ws[WS_TBL + r * 256 + 2 * d + 0] = accW;
    ws[WS_TBL + r * 256 + 2 * d + 1] = accB;
  } else {
    // pack: B-fragment for mfma_f32_16x16x32_bf16:
    // frag (c,kc,lane) elem j = B[k=kc*32+(lane>>4)*8+j][n=c*16+(lane&15)]
    int idx = (blk - 257) * 128 + tid;             // 65536 total
    int j  = idx & 7;
    int l  = (idx >> 3) & 63;
    int kc = (idx >> 9) & 15;
    int c  = idx >> 13;
    int k = kc * 32 + ((l >> 4) * 8) + j;
    int n = c * 16 + (l & 15);
    float x = em_w1[k * H + n];
    unsigned short hb = bfbits(x);
    unsigned short lb = bfbits(x - bf2f(hb));
    ((unsigned short*)(ws + WSB_HI))[idx] = hb;
    ((unsigned short*)(ws + WSB_LO))[idx] = lb;
  }
}

// Attention: each wave owns 4 EDGES; both sides (u,v) concurrently, FOUR keys
// per side per iteration -> 8 independent gather chains, straight-line.
// The 8 per-key wave reductions are done JOINTLY in 6 butterfly steps
// (crossed-select merges; key j lands at lane j(l) = (b0^b2, b1^b2, b2)),
// and the 8 weight exps collapse into ONE vector exp.
// ONLINE-max softmax (scores reach O(1e3); running max mandatory).
// Empty-mask fallback folded in: seed mask with all 20 keys, force scores to
// -1e9 (forced mask applied BEFORE validity mask) -> all weights exp(0)=1,
// ss=20 -> unified normalize reproduces the uniform-1/20 reference exactly.
template<int NB>
__device__ __forceinline__ void run_sides(
    int sbase, int b0, int B, int lane,
    const int* __restrict__ edge_index, const int* __restrict__ edge_ts,
    const int* __restrict__ hist_nb, const int* __restrict__ hist_tm,
    const int* __restrict__ hist_sg,
    const float* __restrict__ node_emb, const float* __restrict__ ws,
    float th0, float th1, float th2, float th3,
    float2 se0, float2 se1, float* __restrict__ zbuf)
{
  const float S = 0.088388347648318447f;   // 1/sqrt(128)
  // loop-invariant butterfly selectors (b0^b2, b1^b2, b2 of lane)
  const bool c1 = (0x5Au >> (lane & 7)) & 1;
  const bool c2 = (0x3Cu >> (lane & 7)) & 1;
  const bool c3 = (lane & 4) != 0;
  const unsigned long long VSIDE = 0xF0F0F0F0F0F0F0F0ull; // V-key lanes

  int eBase = sbase >> 1;                  // 4 edges per wave
  // ---- prefetch edge eBase (both sides) ----
  int eN = b0 + eBase;
  int nU = edge_index[eN];
  int nV = edge_index[B + eN];
  int t_n = edge_ts[eN];
  float2 qU_n = *(const float2*)(node_emb + (size_t)nU * H + 2 * lane);
  float2 qV_n = *(const float2*)(node_emb + (size_t)nV * H + 2 * lane);
  int pkU_n = 0, tmU_n = 0, pkV_n = 0, tmV_n = 0;
  if (lane < K) {
    pkU_n = (hist_nb[nU * K + lane] << 1) | hist_sg[nU * K + lane];
    tmU_n = hist_tm[nU * K + lane];
    pkV_n = (hist_nb[nV * K + lane] << 1) | hist_sg[nV * K + lane];
    tmV_n = hist_tm[nV * K + lane];
  }

  #pragma unroll 1
  for (int p = 0; p < 4; p++) {
    int e = eBase + p;
    int tC = t_n;
    float2 qU = qU_n, qV = qV_n;
    int pkU = pkU_n, tmU = tmU_n, pkV = pkV_n, tmV = tmV_n;
    if (p < 3) {
      int e2 = b0 + e + 1;
      int nU2 = edge_index[e2];
      int nV2 = edge_index[B + e2];
      t_n = edge_ts[e2];
      qU_n = *(const float2*)(node_emb + (size_t)nU2 * H + 2 * lane);
      qV_n = *(const float2*)(node_emb + (size_t)nV2 * H + 2 * lane);
      if (lane < K) {
        pkU_n = (hist_nb[nU2 * K + lane] << 1) | hist_sg[nU2 * K + lane];
        tmU_n = hist_tm[nU2 * K + lane];
        pkV_n = (hist_nb[nV2 * K + lane] << 1) | hist_sg[nV2 * K + lane];
        tmV_n = hist_tm[nV2 * K + lane];
      }
    }

    unsigned long long mU0 = __ballot((lane < K) && (tmU < tC) && (pkU >= 0));
    unsigned long long mV0 = __ballot((lane < K) && (tmV < tC) && (pkV >= 0));
    bool fU = (mU0 == 0), fV = (mV0 == 0);
    unsigned long long mU = fU ? 0xFFFFFull : mU0;
    unsigned long long mV = fV ? 0xFFFFFull : mV0;
    float qUx = qU.x * S, qUy = qU.y * S;
    float qVx = qV.x * S, qVy = qV.y * S;

    float mxU = -3.0e38f, ssU = 0.f, zU0 = 0.f, zU1 = 0.f;
    float mxV = -3.0e38f, ssV = 0.f, zV0 = 0.f, zV1 = 0.f;

    #define RANK4(d) (__popcll(__ballot(th0 < (d))) + __popcll(__ballot(th1 < (d))) \
                      + (NB == 4 ? (__popcll(__ballot(th2 < (d))) + __popcll(__ballot(th3 < (d)))) : 0))

    while (mU | mV) {
      // ---- pop 4 slots per side (SALU chain, cheap)
      bool vUa = mU != 0; int kUa = vUa ? __ffsll((long long)mU) - 1 : 0; mU &= mU - 1;
      bool vUb = mU != 0; int kUb = vUb ? __ffsll((long long)mU) - 1 : 0; mU &= mU - 1;
      bool vUc = mU != 0; int kUc = vUc ? __ffsll((long long)mU) - 1 : 0; mU &= mU - 1;
      bool vUd = mU != 0; int kUd = vUd ? __ffsll((long long)mU) - 1 : 0; mU &= mU - 1;
      bool vVa = mV != 0; int kVa = vVa ? __ffsll((long long)mV) - 1 : 0; mV &= mV - 1;
      bool vVb = mV != 0; int kVb = vVb ? __ffsll((long long)mV) - 1 : 0; mV &= mV - 1;
      bool vVc = mV != 0; int kVc = vVc ? __ffsll((long long)mV) - 1 : 0; mV &= mV - 1;
      bool vVd = mV != 0; int kVd = vVd ? __ffsll((long long)mV) - 1 : 0; mV &= mV - 1;

      // ---- metadata (readlane -> wave-uniform)
      int tmUa = __builtin_amdgcn_readlane(tmU, kUa), pkUa = __builtin_amdgcn_readlane(pkU, kUa);
      int tmUb = __builtin_amdgcn_readlane(tmU, kUb), pkUb = __builtin_amdgcn_readlane(pkU, kUb);
      int tmUc = __builtin_amdgcn_readlane(tmU, kUc), pkUc = __builtin_amdgcn_readlane(pkU, kUc);
      int tmUd = __builtin_amdgcn_readlane(tmU, kUd), pkUd = __builtin_amdgcn_readlane(pkU, kUd);
      int tmVa = __builtin_amdgcn_readlane(tmV, kVa), pkVa = __builtin_amdgcn_readlane(pkV, kVa);
      int tmVb = __builtin_amdgcn_readlane(tmV, kVb), pkVb = __builtin_amdgcn_readlane(pkV, kVb);
      int tmVc = __builtin_amdgcn_readlane(tmV, kVc), pkVc = __builtin_amdgcn_readlane(pkV, kVc);
      int tmVd = __builtin_amdgcn_readlane(tmV, kVd), pkVd = __builtin_amdgcn_readlane(pkV, kVd);

      float dUa = (float)(tC - tmUa), dUb = (float)(tC - tmUb);
      float dUc = (float)(tC - tmUc), dUd = (float)(tC - tmUd);
      float dVa = (float)(tC - tmVa), dVb = (float)(tC - tmVb);
      float dVc = (float)(tC - tmVc), dVd = (float)(tC - tmVd);

      int rUa = RANK4(dUa), rUb = RANK4(dUb), rUc = RANK4(dUc), rUd = RANK4(dUd);
      int rVa = RANK4(dVa), rVb = RANK4(dVb), rVc = RANK4(dVc), rVd = RANK4(dVd);

      // ---- 16 independent gathers, all in flight together
      const float4 tbUa = *(const float4*)(ws + WS_TBL + rUa * 256 + 4 * lane);
      const float4 tbUb = *(const float4*)(ws + WS_TBL + rUb * 256 + 4 * lane);
      const float4 tbUc = *(const float4*)(ws + WS_TBL + rUc * 256 + 4 * lane);
      const float4 tbUd = *(const float4*)(ws + WS_TBL + rUd * 256 + 4 * lane);
      const float4 tbVa = *(const float4*)(ws + WS_TBL + rVa * 256 + 4 * lane);
      const float4 tbVb = *(const float4*)(ws + WS_TBL + rVb * 256 + 4 * lane);
      const float4 tbVc = *(const float4*)(ws + WS_TBL + rVc * 256 + 4 * lane);
      const float4 tbVd = *(const float4*)(ws + WS_TBL + rVd * 256 + 4 * lane);
      float2 neUa = *(const float2*)(node_emb + (size_t)(pkUa >> 1) * H + 2 * lane);
      float2 neUb = *(const float2*)(node_emb + (size_t)(pkUb >> 1) * H + 2 * lane);
      float2 neUc = *(const float2*)(node_emb + (size_t)(pkUc >> 1) * H + 2 * lane);
      float2 neUd = *(const float2*)(node_emb + (size_t)(pkUd >> 1) * H + 2 * lane);
      float2 neVa = *(const float2*)(node_emb + (size_t)(pkVa >> 1) * H + 2 * lane);
      float2 neVb = *(const float2*)(node_emb + (size_t)(pkVb >> 1) * H + 2 * lane);
      float2 neVc = *(const float2*)(node_emb + (size_t)(pkVc >> 1) * H + 2 * lane);
      float2 neVd = *(const float2*)(node_emb + (size_t)(pkVd >> 1) * H + 2 * lane);

      // ---- build keys (needed in full for the z accumulation)
      float kU0a = neUa.x + ((pkUa & 1) ? se1.x : se0.x) + dUa * tbUa.x + tbUa.y;
      float kU1a = neUa.y + ((pkUa & 1) ? se1.y : se0.y) + dUa * tbUa.z + tbUa.w;
      float kU0b = neUb.x + ((pkUb & 1) ? se1.x : se0.x) + dUb * tbUb.x + tbUb.y;
      float kU1b = neUb.y + ((pkUb & 1) ? se1.y : se0.y) + dUb * tbUb.z + tbUb.w;
      float kU0c = neUc.x + ((pkUc & 1) ? se1.x : se0.x) + dUc * tbUc.x + tbUc.y;
      float kU1c = neUc.y + ((pkUc & 1) ? se1.y : se0.y) + dUc * tbUc.z + tbUc.w;
      float kU0d = neUd.x + ((pkUd & 1) ? se1.x : se0.x) + dUd * tbUd.x + tbUd.y;
      float kU1d = neUd.y + ((pkUd & 1) ? se1.y : se0.y) + dUd * tbUd.z + tbUd.w;
      float kV0a = neVa.x + ((pkVa & 1) ? se1.x : se0.x) + dVa * tbVa.x + tbVa.y;
      float kV1a = neVa.y + ((pkVa & 1) ? se1.y : se0.y) + dVa * tbVa.z + tbVa.w;
      float kV0b = neVb.x + ((pkVb & 1) ? se1.x : se0.x) + dVb * tbVb.x + tbVb.y;
      float kV1b = neVb.y + ((pkVb & 1) ? se1.y : se0.y) + dVb * tbVb.z + tbVb.w;
      float kV0c = neVc.x + ((pkVc & 1) ? se1.x : se0.x) + dVc * tbVc.x + tbVc.y;
      float kV1c = neVc.y + ((pkVc & 1) ? se1.y : se0.y) + dVc * tbVc.z + tbVc.w;
      float kV0d = neVd.x + ((pkVd & 1) ? se1.x : se0.x) + dVd * tbVd.x + tbVd.y;
      float kV1d = neVd.y + ((pkVd & 1) ? se1.y : se0.y) + dVd * tbVd.z + tbVd.w;

      // ---- per-lane dot partials (key order: Ua Ub Uc Ud Va Vb Vc Vd)
      float p0 = qUx * kU0a + qUy * kU1a;
      float p1 = qUx * kU0b + qUy * kU1b;
      float p2 = qUx * kU0c + qUy * kU1c;
      float p3 = qUx * kU0d + qUy * kU1d;
      float p4 = qVx * kV0a + qVy * kV1a;
      float p5 = qVx * kV0b + qVy * kV1b;
      float p6 = qVx * kV0c + qVy * kV1c;
      float p7 = qVx * kV0d + qVy * kV1d;

      // ---- joint 8-way butterfly reduction (6 steps)
      float q0 = merge2<0xB1>(p0, p1, c1);
      float q1 = merge2<0xB1>(p2, p3, c1);
      float q2 = merge2<0xB1>(p4, p5, c1);
      float q3 = merge2<0xB1>(p6, p7, c1);
      float t0 = merge2<0x4E>(q0, q1, c2);
      float t1 = merge2<0x4E>(q2, q3, c2);
      float r  = merge2<0x141>(t0, t1, c3);
      r += dpp_mov<0x128>(r);          // xor8 (row_ror:8)
      r += __shfl_xor(r, 16);
      r += __shfl_xor(r, 32);
      // lane l holds full sum of key j(l); U keys at lanes 0-3,
      // V keys at lanes 7,6,5,4 (mod 8)

      // ---- masking: forced FIRST, then validity
      unsigned long long fmask =
          (fU ? 0x0F0F0F0F0F0F0F0Full : 0ull) |
          (fV ? 0xF0F0F0F0F0F0F0F0ull : 0ull);
      unsigned long long smask =
          (vUa ? 0x0101010101010101ull : 0ull) |
          (vUb ? 0x0202020202020202ull : 0ull) |
          (vUc ? 0x0404040404040404ull : 0ull) |
          (vUd ? 0x0808080808080808ull : 0ull) |
          (vVd ? 0x1010101010101010ull : 0ull) |
          (vVc ? 0x2020202020202020ull : 0ull) |
          (vVb ? 0x4040404040404040ull : 0ull) |
          (vVa ? 0x8080808080808080ull : 0ull);
      float rv, neg9 = -1e9f, neg38 = -3.0e38f;
      asm("v_cndmask_b32 %0, %1, %2, %3" : "=v"(rv) : "v"(r), "v"(neg9), "s"(fmask));
      asm("v_cndmask_b32 %0, %1, %2, %3" : "=v"(rv) : "v"(neg38), "v"(rv), "s"(smask));

      // ---- per-side 4-max in lanes, then running max + rescale
      float m1 = fmaxf(rv, dpp_mov<0xB1>(rv));
      float m2 = fmaxf(m1, dpp_mov<0x4E>(m1));
      float mnU = fmaxf(mxU, rdlane<0>(m2));
      float mnV = fmaxf(mxV, rdlane<4>(m2));
      float alU = __expf(mxU - mnU);
      float alV = __expf(mxV - mnV);
      mxU = mnU; mxV = mnV;
      float mnl;
      asm("v_cndmask_b32 %0, %1, %2, %3" : "=v"(mnl) : "v"(mnU), "v"(mnV), "s"(VSIDE));
      float wvec = __expf(rv - mnl);    // ONE exp for all 8 weights

      float wUa = rdlane<0>(wvec), wUb = rdlane<1>(wvec);
      float wUc = rdlane<2>(wvec), wUd = rdlane<3>(wvec);
      float wVa = rdlane<7>(wvec), wVb = rdlane<6>(wvec);
      float wVc = rdlane<5>(wvec), wVd = rdlane<4>(wvec);

      ssU = ssU * alU + ((wUa + wUb) + (wUc + wUd));
      zU0 = zU0 * alU + ((wUa * kU0a + wUb * kU0b) + (wUc * kU0c + wUd * kU0d));
      zU1 = zU1 * alU + ((wUa * kU1a + wUb * kU1b) + (wUc * kU1c + wUd * kU1d));
      ssV = ssV * alV + ((wVa + wVb) + (wVc + wVd));
      zV0 = zV0 * alV + ((wVa * kV0a + wVb * kV0b) + (wVc * kV0c + wVd * kV0d));
      zV1 = zV1 * alV + ((wVa * kV1a + wVb * kV1b) + (wVc * kV1c + wVd * kV1d));
    }
    #undef RANK4

    // unified normalize: fallback sides have ss == 20.0 exactly
    float invU = 1.f / ssU; zU0 *= invU; zU1 *= invU;
    float invV = 1.f / ssV; zV0 *= invV; zV1 *= invV;

    int sw = (e & 7) << 1;
    int ccU = lane ^ sw;
    int ccV = (64 + lane) ^ sw;
    *(float2*)&zbuf[(e << 8) + (ccU << 1)] = make_float2(zU0, zU1);
    *(float2*)&zbuf[(e << 8) + (ccV << 1)] = make_float2(zV0, zV1);
  }
}

// Main fused kernel: 4 waves/block, each wave owns 4 edges (8 sides) with
// dual-side + quad-key ILP (8 chains) and joint butterfly reduction.
// bounds(256,4): VGPR cap 128. zu/zv XOR-swizzled in 16 KB LDS;
// MLP layer 1 via split-bf16 MFMA with derived columns built on the fly.
__global__ __launch_bounds__(256, 4) void tgat_main_kernel(
    const int* __restrict__ edge_index, const int* __restrict__ edge_ts,
    const int* __restrict__ hist_nb, const int* __restrict__ hist_tm,
    const int* __restrict__ hist_sg,
    const float* __restrict__ node_emb, const float* __restrict__ sign_emb,
    const float* __restrict__ em_b1,
    const float* __restrict__ em_w2, const float* __restrict__ em_b2,
    const float* __restrict__ ws, float* __restrict__ out, int B)
{
  // zbuf rows = 16 edges, 256 floats (zu|zv) per row, float2-chunk XOR swizzle:
  // logical chunk c of row e stored at chunk c ^ ((e&7)<<1). 16 KB total.
  __shared__ __align__(16) float zbuf[EPB * 256];

  int tid = threadIdx.x;
  int lane = tid & 63;
  int wv = __builtin_amdgcn_readfirstlane(tid >> 6);
  int b0 = blockIdx.x * EPB;

  int M = ((const int*)(ws + WS_CNT))[0];
  float th0 = (lane       < M) ? ws[WS_THM + lane      ] : 3.0e38f;
  float th1 = (lane + 64  < M) ? ws[WS_THM + lane + 64 ] : 3.0e38f;
  float2 se0 = *(const float2*)(sign_emb + 2 * lane);
  float2 se1 = *(const float2*)(sign_emb + H + 2 * lane);

  int sbase = wv * 8;
  if (M <= 128) {
    run_sides<2>(sbase, b0, B, lane, edge_index, edge_ts, hist_nb, hist_tm,
                 hist_sg, node_emb, ws, th0, th1, 3.0e38f, 3.0e38f,
                 se0, se1, zbuf);
  } else {
    float th2 = (lane + 128 < M) ? ws[WS_THM + lane + 128] : 3.0e38f;
    float th3 = (lane + 192 < M) ? ws[WS_THM + lane + 192] : 3.0e38f;
    run_sides<4>(sbase, b0, B, lane, edge_index, edge_ts, hist_nb, hist_tm,
                 hist_sg, node_emb, ws, th0, th1, th2, th3,
                 se0, se1, zbuf);
  }
  __syncthreads();

  // ---- MLP layer 1 via split-bf16 MFMA: hid[16][128] = feat[16][512] @ em_w1
  // feat regions: [zu | zv | |zu-zv| | zu*zv], built on the fly from zbuf.
  const unsigned short* whi = (const unsigned short*)(ws + WSB_HI);
  const unsigned short* wlo = (const unsigned short*)(ws + WSB_LO);
  int c0 = 2 * wv;
  int m_ = lane & 15;
  int qd = lane >> 4;
  int sw = (m_ & 7) << 1;
  const float* zrow = zbuf + (m_ << 8);
  f32x4 acc0 = {0.f, 0.f, 0.f, 0.f};
  f32x4 acc1 = {0.f, 0.f, 0.f, 0.f};
  #pragma unroll
  for (int kc = 0; kc < 16; kc++) {
    const int reg = kc >> 2;
    int cb = (kc & 3) * 16 + qd * 4;     // base chunk within a 128-dim region
    float av[8];
    if (reg == 0) {
      float4 A0 = *(const float4*)(zrow + (((cb    ) ^ sw) << 1));
      float4 A1 = *(const float4*)(zrow + (((cb + 2) ^ sw) << 1));
      av[0]=A0.x; av[1]=A0.y; av[2]=A0.z; av[3]=A0.w;
      av[4]=A1.x; av[5]=A1.y; av[6]=A1.z; av[7]=A1.w;
    } else if (reg == 1) {
      float4 A0 = *(const float4*)(zrow + (((cb + 64) ^ sw) << 1));
      float4 A1 = *(const float4*)(zrow + (((cb + 66) ^ sw) << 1));
      av[0]=A0.x; av[1]=A0.y; av[2]=A0.z; av[3]=A0.w;
      av[4]=A1.x; av[5]=A1.y; av[6]=A1.z; av[7]=A1.w;
    } else {
      float4 U0 = *(const float4*)(zrow + (((cb    ) ^ sw) << 1));
      float4 U1 = *(const float4*)(zrow + (((cb + 2) ^ sw) << 1));
      float4 V0 = *(const float4*)(zrow + (((cb + 64) ^ sw) << 1));
      float4 V1 = *(const float4*)(zrow + (((cb + 66) ^ sw) << 1));
      float uu[8] = {U0.x,U0.y,U0.z,U0.w,U1.x,U1.y,U1.z,U1.w};
      float vvv[8] = {V0.x,V0.y,V0.z,V0.w,V1.x,V1.y,V1.z,V1.w};
      if (reg == 2) {
        #pragma unroll
        for (int j = 0; j < 8; j++) av[j] = fabsf(uu[j] - vvv[j]);
      } else {
        #pragma unroll
        for (int j = 0; j < 8; j++) av[j] = uu[j] * vvv[j];
      }
    }
    // split-bf16 A fragments: hi = bit-truncation (v_perm pack, 1 op/pair),
    // lo = exact residual (Sterbenz) rounded-ne as a packed pair.
    union { short8 v; unsigned u[4]; } ahi, alo;
    #pragma unroll
    for (int j = 0; j < 4; j++) {
      unsigned b0u = __float_as_uint(av[2 * j]);
      unsigned b1u = __float_as_uint(av[2 * j + 1]);
      ahi.u[j] = __builtin_amdgcn_perm(b1u, b0u, 0x07060302u);
      float l0 = av[2 * j]     - __uint_as_float(b0u & 0xFFFF0000u);
      float l1 = av[2 * j + 1] - __uint_as_float(b1u & 0xFFFF0000u);
      __hip_bfloat162 lp = __float22bfloat162_rn(make_float2(l0, l1));
      __builtin_memcpy(&alo.u[j], &lp, 4);
    }
    int f0 = (((c0    ) * 16 + kc) * 64 + lane) * 8;
    int f1 = (((c0 + 1) * 16 + kc) * 64 + lane) * 8;
    short8 bh0 = *(const short8*)(whi + f0);
    short8 bl0 = *(const short8*)(wlo + f0);
    short8 bh1 = *(const short8*)(whi + f1);
    short8 bl1 = *(const short8*)(wlo + f1);
    acc0 = __builtin_amdgcn_mfma_f32_16x16x32_bf16(ahi.v, bh0, acc0, 0, 0, 0);
    acc0 = __builtin_amdgcn_mfma_f32_16x16x32_bf16(ahi.v, bl0, acc0, 0, 0, 0);
    acc0 = __builtin_amdgcn_mfma_f32_16x16x32_bf16(alo.v, bh0, acc0, 0, 0, 0);
    acc1 = __builtin_amdgcn_mfma_f32_16x16x32_bf16(ahi.v, bh1, acc1, 0, 0, 0);
    acc1 = __builtin_amdgcn_mfma_f32_16x16x32_bf16(ahi.v, bl1, acc1, 0, 0, 0);
    acc1 = __builtin_amdgcn_mfma_f32_16x16x32_bf16(alo.v, bh1, acc1, 0, 0, 0);
  }
  __syncthreads();   // all A-reads of zbuf complete before overlay reuse

  // bias + relu, write hid into zbuf overlay (stride 132)
  float* hp = zbuf;
  float eb0 = em_b1[c0 * 16 + m_];
  float eb1 = em_b1[(c0 + 1) * 16 + m_];
  #pragma unroll
  for (int r = 0; r < 4; r++) {
    int edge = qd * 4 + r;
    hp[edge * 132 + c0 * 16 + m_]       = fmaxf(acc0[r] + eb0, 0.f);
    hp[edge * 132 + (c0 + 1) * 16 + m_] = fmaxf(acc1[r] + eb1, 0.f);
  }
  __syncthreads();

  // ---- layer 2: logits = hid @ em_w2 + em_b2 ; wave wv does edges wv*4..+3
  float2 w2v = *(const float2*)(em_w2 + 2 * lane);
  float bias2 = em_b2[0];
  #pragma unroll
  for (int i = 0; i < 4; i++) {
    int e = wv * 4 + i;
    int b = b0 + e;
    float2 hv = *(const float2*)(hp + e * 132 + 2 * lane);
    float p = wave_sum63(hv.x * w2v.x + hv.y * w2v.y);
    float ps = bcast63(p);
    if (lane == 0 && b < B) out[b] = ps + bias2;
  }
}

extern "C" void kernel_launch(void* const* d_in, const int* in_sizes, int n_in,
                              void* d_out, int out_size, void* d_ws, size_t ws_size,
                              hipStream_t stream)
{
  (void)n_in; (void)out_size; (void)ws_size;
  const int* edge_index = (const int*)d_in[0];
  const int* edge_ts    = (const int*)d_in[1];
  const int* hist_nb    = (const int*)d_in[2];
  const int* hist_tm    = (const int*)d_in[3];
  const int* hist_sg    = (const int*)d_in[4];
  const float* node_emb = (const float*)d_in[5];
  const float* sign_emb = (const float*)d_in[6];
  const float* tp_w1    = (const float*)d_in[7];
  const float* tp_b1    = (const float*)d_in[8];
  const float* tp_w2    = (const float*)d_in[9];
  const float* tp_b2    = (const float*)d_in[10];
  const float* em_w1    = (const float*)d_in[11];
  const float* em_b1    = (const float*)d_in[12];
  const float* em_w2    = (const float*)d_in[13];
  const float* em_b2    = (const float*)d_in[14];
  float* out = (float*)d_out;
  float* ws  = (float*)d_ws;
  int B = in_sizes[1];

  hipLaunchKernelGGL(aux_kernel, dim3(769), dim3(128), 0, stream,
                     tp_w1, tp_b1, tp_w2, tp_b2, em_w1, ws);
  int grid = (B + EPB - 1) / EPB;
  hipLaunchKernelGGL(tgat_main_kernel, dim3(grid), dim3(256), 0, stream,
                     edge_index, edge_ts, hist_nb, hist_tm, hist_sg,
                     node_emb, sign_emb, em_b1, em_w2, em_b2, ws, out, B);
}

// Round 6
// 355.184 us; speedup vs baseline: 1.1004x; 1.1004x over previous
//
#include <hip/hip_runtime.h>
#include <hip/hip_bf16.h>
#include <math.h>

#define H 128
#define K 20
#define EPB 16        // edges per block (M=16 for MFMA)

// ---- workspace layout (float offsets) ----
#define WS_TBL    0            // merged table: 257 rows x 256 floats {W,B}
#define WS_THM    65792        // 256 merged sorted thresholds
#define WS_CNT    66176        // 1 int: M = nP + nN
#define WSB_HI    67072        // 65536 ushort: em_w1 bf16-hi, B-fragment order
#define WSB_LO    99840        // 65536 ushort: em_w1 bf16-lo

typedef __attribute__((ext_vector_type(8))) short short8;
typedef __attribute__((ext_vector_type(4))) float f32x4;

// DPP-based wave64 sum; result valid in lane 63. (used by MLP tail)
template<int CTRL, int RMASK>
__device__ __forceinline__ float dpp_add(float x) {
  int y = __builtin_amdgcn_update_dpp(0, __float_as_int(x), CTRL, RMASK, 0xf, true);
  return x + __int_as_float(y);
}
__device__ __forceinline__ float wave_sum63(float x) {
  x = dpp_add<0xB1,  0xf>(x);
  x = dpp_add<0x4E,  0xf>(x);
  x = dpp_add<0x141, 0xf>(x);
  x = dpp_add<0x140, 0xf>(x);
  x = dpp_add<0x142, 0xa>(x);
  x = dpp_add<0x143, 0xc>(x);
  return x;
}
__device__ __forceinline__ float bcast63(float x) {
  return __int_as_float(__builtin_amdgcn_readlane(__float_as_int(x), 63));
}

// DPP lane-permute mov (full row/bank masks, bound_ctrl=1)
template<int CTRL>
__device__ __forceinline__ float dpp_mov(float x) {
  return __int_as_float(
      __builtin_amdgcn_update_dpp(0, __float_as_int(x), CTRL, 0xf, 0xf, true));
}
template<int L>
__device__ __forceinline__ float rdlane(float x) {
  return __int_as_float(__builtin_amdgcn_readlane(__float_as_int(x), L));
}
// Crossed-select merge (verified on HW in R5): out[l] = Z_b[l] + Z_b[l^1],
// b = beta(l); requires beta(l^1) != beta(l).
template<int CTRL>
__device__ __forceinline__ float merge2(float z0, float z1, bool beta) {
  float keep = beta ? z1 : z0;
  float sel  = beta ? z0 : z1;
  return keep + dpp_mov<CTRL>(sel);
}
// Joint 2-key all-lane reduction keeping chains independent:
// even lanes end with key0's full 64-lane sum, odd lanes key1's.
// All steps after the xor1-merge preserve bit0 of the lane id.
__device__ __forceinline__ float red2(float z0, float z1, bool b0) {
  float r = merge2<0xB1>(z0, z1, b0);   // quad_perm xor1 (crossed-select)
  r += dpp_mov<0x4E>(r);                // quad_perm xor2
  r += dpp_mov<0x124>(r);               // row_ror:4
  r += dpp_mov<0x128>(r);               // row_ror:8
  r += __shfl_xor(r, 16);
  r += __shfl_xor(r, 32);
  return r;
}

__device__ __forceinline__ unsigned short bfbits(float x) {
  __hip_bfloat16 h = __float2bfloat16(x);
  unsigned short u; __builtin_memcpy(&u, &h, 2); return u;
}
__device__ __forceinline__ float bf2f(unsigned short u) {
  return __uint_as_float(((unsigned)u) << 16);
}

// Single fused aux kernel (769 blocks x 128 threads):
//  blocks 0..256  : locally recompute the threshold sort, then build merged-
//                   table row r = blockIdx (block 0 also publishes THM/CNT).
//  blocks 257..768: pack em_w1 into bf16 hi/lo planes, B-fragment order.
__global__ __launch_bounds__(128) void aux_kernel(
    const float* __restrict__ w1v, const float* __restrict__ b1v,
    const float* __restrict__ w2, const float* __restrict__ b2,
    const float* __restrict__ em_w1, float* __restrict__ ws)
{
  int blk = blockIdx.x;
  int tid = threadIdx.x;
  if (blk < 257) {
    __shared__ float th[H];
    __shared__ int grp[H];
    __shared__ int sidx[2 * H];
    __shared__ int Msh;
    float w = w1v[tid], b = b1v[tid];
    int g = (w > 0.f) ? 0 : ((w < 0.f) ? 1 : 2);   // 0=P, 1=N, 2=Z
    float t = (g == 2) ? 0.f : (-b / w);
    th[tid] = t; grp[tid] = g;
    if (tid == 0) Msh = 0;
    __syncthreads();
    if (g != 2) {
      int r = 0;
      for (int i = 0; i < H; i++)
        if (grp[i] != 2 && (th[i] < t || (th[i] == t && i < tid))) r++;
      sidx[r] = (tid << 1) | (g == 0 ? 1 : 0);     // bit0 = isP
      atomicAdd(&Msh, 1);
      if (blk == 0) ws[WS_THM + r] = t;            // publish for main
    }
    __syncthreads();
    int M = Msh;
    if (blk == 0 && tid == 0) ((int*)(ws + WS_CNT))[0] = M;
    int r = blk;
    if (r > M) return;
    int d = tid;
    // BASE[d] = tp_b2[d] + sum over (w1==0, b1>0) of b1*w2[h][d]
    float accW = 0.f, accB = b2[d];
    for (int i = 0; i < H; i++)
      if (grp[i] == 2 && b1v[i] > 0.f) accB += b1v[i] * w2[i * H + d];
    #pragma unroll 4
    for (int i = 0; i < M; i++) {
      int ent = sidx[i];
      int h = ent >> 1;
      int isP = ent & 1;
      int take = (i < r) ? isP : (1 - isP);
      if (take) {
        float wv = w2[h * H + d];
        accW += w1v[h] * wv;
        accB += b1v[h] * wv;
      }
    }
    ws[WS_TBL + r * 256 + 2 * d + 0] = accW;
    ws[WS_TBL + r * 256 + 2 * d + 1] = accB;
  } else {
    // pack: B-fragment for mfma_f32_16x16x32_bf16:
    // frag (c,kc,lane) elem j = B[k=kc*32+(lane>>4)*8+j][n=c*16+(lane&15)]
    int idx = (blk - 257) * 128 + tid;             // 65536 total
    int j  = idx & 7;
    int l  = (idx >> 3) & 63;
    int kc = (idx >> 9) & 15;
    int c  = idx >> 13;
    int k = kc * 32 + ((l >> 4) * 8) + j;
    int n = c * 16 + (l & 15);
    float x = em_w1[k * H + n];
    unsigned short hb = bfbits(x);
    unsigned short lb = bfbits(x - bf2f(hb));
    ((unsigned short*)(ws + WSB_HI))[idx] = hb;
    ((unsigned short*)(ws + WSB_LO))[idx] = lb;
  }
}

// Attention: each wave owns 4 EDGES; both sides (u,v) concurrently, FOUR keys
// per side per iteration, straight-line select-guarded body.
// All 16 gathers are pinned in flight by a sched_barrier before any consume
// (one latency exposure per iteration). The 8 per-key reductions run as 4
// independent pairwise chains (red2): ILP preserved, ~40 fewer VALU/iter.
// ONLINE-max softmax (scores reach O(1e3); running max mandatory).
// Empty-mask fallback folded in: seed mask with all 20 keys, force scores to
// -1e9 -> max=-1e9, all weights exp(0)=1, ss=20 -> unified normalize
// reproduces the uniform-1/20 reference path exactly.
template<int NB>
__device__ __forceinline__ void run_sides(
    int sbase, int b0, int B, int lane,
    const int* __restrict__ edge_index, const int* __restrict__ edge_ts,
    const int* __restrict__ hist_nb, const int* __restrict__ hist_tm,
    const int* __restrict__ hist_sg,
    const float* __restrict__ node_emb, const float* __restrict__ ws,
    float th0, float th1, float th2, float th3,
    float2 se0, float2 se1, float* __restrict__ zbuf)
{
  const float S = 0.088388347648318447f;   // 1/sqrt(128)
  const bool b0sel = (lane & 1) != 0;
  int eBase = sbase >> 1;                  // 4 edges per wave
  // ---- prefetch edge eBase (both sides) ----
  int eN = b0 + eBase;
  int nU = edge_index[eN];
  int nV = edge_index[B + eN];
  int t_n = edge_ts[eN];
  float2 qU_n = *(const float2*)(node_emb + (size_t)nU * H + 2 * lane);
  float2 qV_n = *(const float2*)(node_emb + (size_t)nV * H + 2 * lane);
  int pkU_n = 0, tmU_n = 0, pkV_n = 0, tmV_n = 0;
  if (lane < K) {
    pkU_n = (hist_nb[nU * K + lane] << 1) | hist_sg[nU * K + lane];
    tmU_n = hist_tm[nU * K + lane];
    pkV_n = (hist_nb[nV * K + lane] << 1) | hist_sg[nV * K + lane];
    tmV_n = hist_tm[nV * K + lane];
  }

  #pragma unroll 1
  for (int p = 0; p < 4; p++) {
    int e = eBase + p;
    int tC = t_n;
    float2 qU = qU_n, qV = qV_n;
    int pkU = pkU_n, tmU = tmU_n, pkV = pkV_n, tmV = tmV_n;
    if (p < 3) {
      int e2 = b0 + e + 1;
      int nU2 = edge_index[e2];
      int nV2 = edge_index[B + e2];
      t_n = edge_ts[e2];
      qU_n = *(const float2*)(node_emb + (size_t)nU2 * H + 2 * lane);
      qV_n = *(const float2*)(node_emb + (size_t)nV2 * H + 2 * lane);
      if (lane < K) {
        pkU_n = (hist_nb[nU2 * K + lane] << 1) | hist_sg[nU2 * K + lane];
        tmU_n = hist_tm[nU2 * K + lane];
        pkV_n = (hist_nb[nV2 * K + lane] << 1) | hist_sg[nV2 * K + lane];
        tmV_n = hist_tm[nV2 * K + lane];
      }
    }

    unsigned long long mU0 = __ballot((lane < K) && (tmU < tC) && (pkU >= 0));
    unsigned long long mV0 = __ballot((lane < K) && (tmV < tC) && (pkV >= 0));
    bool fU = (mU0 == 0), fV = (mV0 == 0);
    unsigned long long mU = fU ? 0xFFFFFull : mU0;
    unsigned long long mV = fV ? 0xFFFFFull : mV0;
    float qUx = qU.x * S, qUy = qU.y * S;
    float qVx = qV.x * S, qVy = qV.y * S;

    float mxU = -3.0e38f, ssU = 0.f, zU0 = 0.f, zU1 = 0.f;
    float mxV = -3.0e38f, ssV = 0.f, zV0 = 0.f, zV1 = 0.f;

    #define RANK4(d) (__popcll(__ballot(th0 < (d))) + __popcll(__ballot(th1 < (d))) \
                      + (NB == 4 ? (__popcll(__ballot(th2 < (d))) + __popcll(__ballot(th3 < (d)))) : 0))

    while (mU | mV) {
      // ---- pop 4 slots per side (SALU chain, cheap)
      bool vUa = mU != 0; int kUa = vUa ? __ffsll((long long)mU) - 1 : 0; mU &= mU - 1;
      bool vUb = mU != 0; int kUb = vUb ? __ffsll((long long)mU) - 1 : 0; mU &= mU - 1;
      bool vUc = mU != 0; int kUc = vUc ? __ffsll((long long)mU) - 1 : 0; mU &= mU - 1;
      bool vUd = mU != 0; int kUd = vUd ? __ffsll((long long)mU) - 1 : 0; mU &= mU - 1;
      bool vVa = mV != 0; int kVa = vVa ? __ffsll((long long)mV) - 1 : 0; mV &= mV - 1;
      bool vVb = mV != 0; int kVb = vVb ? __ffsll((long long)mV) - 1 : 0; mV &= mV - 1;
      bool vVc = mV != 0; int kVc = vVc ? __ffsll((long long)mV) - 1 : 0; mV &= mV - 1;
      bool vVd = mV != 0; int kVd = vVd ? __ffsll((long long)mV) - 1 : 0; mV &= mV - 1;

      // ---- metadata (readlane -> wave-uniform)
      int tmUa = __builtin_amdgcn_readlane(tmU, kUa), pkUa = __builtin_amdgcn_readlane(pkU, kUa);
      int tmUb = __builtin_amdgcn_readlane(tmU, kUb), pkUb = __builtin_amdgcn_readlane(pkU, kUb);
      int tmUc = __builtin_amdgcn_readlane(tmU, kUc), pkUc = __builtin_amdgcn_readlane(pkU, kUc);
      int tmUd = __builtin_amdgcn_readlane(tmU, kUd), pkUd = __builtin_amdgcn_readlane(pkU, kUd);
      int tmVa = __builtin_amdgcn_readlane(tmV, kVa), pkVa = __builtin_amdgcn_readlane(pkV, kVa);
      int tmVb = __builtin_amdgcn_readlane(tmV, kVb), pkVb = __builtin_amdgcn_readlane(pkV, kVb);
      int tmVc = __builtin_amdgcn_readlane(tmV, kVc), pkVc = __builtin_amdgcn_readlane(pkV, kVc);
      int tmVd = __builtin_amdgcn_readlane(tmV, kVd), pkVd = __builtin_amdgcn_readlane(pkV, kVd);

      float dUa = (float)(tC - tmUa), dUb = (float)(tC - tmUb);
      float dUc = (float)(tC - tmUc), dUd = (float)(tC - tmUd);
      float dVa = (float)(tC - tmVa), dVb = (float)(tC - tmVb);
      float dVc = (float)(tC - tmVc), dVd = (float)(tC - tmVd);

      int rUa = RANK4(dUa), rUb = RANK4(dUb), rUc = RANK4(dUc), rUd = RANK4(dUd);
      int rVa = RANK4(dVa), rVb = RANK4(dVb), rVc = RANK4(dVc), rVd = RANK4(dVd);

      // ---- 16 independent gathers, ALL issued before any consume
      const float4 tbUa = *(const float4*)(ws + WS_TBL + rUa * 256 + 4 * lane);
      const float4 tbUb = *(const float4*)(ws + WS_TBL + rUb * 256 + 4 * lane);
      const float4 tbUc = *(const float4*)(ws + WS_TBL + rUc * 256 + 4 * lane);
      const float4 tbUd = *(const float4*)(ws + WS_TBL + rUd * 256 + 4 * lane);
      const float4 tbVa = *(const float4*)(ws + WS_TBL + rVa * 256 + 4 * lane);
      const float4 tbVb = *(const float4*)(ws + WS_TBL + rVb * 256 + 4 * lane);
      const float4 tbVc = *(const float4*)(ws + WS_TBL + rVc * 256 + 4 * lane);
      const float4 tbVd = *(const float4*)(ws + WS_TBL + rVd * 256 + 4 * lane);
      float2 neUa = *(const float2*)(node_emb + (size_t)(pkUa >> 1) * H + 2 * lane);
      float2 neUb = *(const float2*)(node_emb + (size_t)(pkUb >> 1) * H + 2 * lane);
      float2 neUc = *(const float2*)(node_emb + (size_t)(pkUc >> 1) * H + 2 * lane);
      float2 neUd = *(const float2*)(node_emb + (size_t)(pkUd >> 1) * H + 2 * lane);
      float2 neVa = *(const float2*)(node_emb + (size_t)(pkVa >> 1) * H + 2 * lane);
      float2 neVb = *(const float2*)(node_emb + (size_t)(pkVb >> 1) * H + 2 * lane);
      float2 neVc = *(const float2*)(node_emb + (size_t)(pkVc >> 1) * H + 2 * lane);
      float2 neVd = *(const float2*)(node_emb + (size_t)(pkVd >> 1) * H + 2 * lane);
      // pin: no consume may be scheduled above this point, no load below
      __builtin_amdgcn_sched_barrier(0);

      // ---- build keys (needed in full for the z accumulation)
      float kU0a = neUa.x + ((pkUa & 1) ? se1.x : se0.x) + dUa * tbUa.x + tbUa.y;
      float kU1a = neUa.y + ((pkUa & 1) ? se1.y : se0.y) + dUa * tbUa.z + tbUa.w;
      float kU0b = neUb.x + ((pkUb & 1) ? se1.x : se0.x) + dUb * tbUb.x + tbUb.y;
      float kU1b = neUb.y + ((pkUb & 1) ? se1.y : se0.y) + dUb * tbUb.z + tbUb.w;
      float kU0c = neUc.x + ((pkUc & 1) ? se1.x : se0.x) + dUc * tbUc.x + tbUc.y;
      float kU1c = neUc.y + ((pkUc & 1) ? se1.y : se0.y) + dUc * tbUc.z + tbUc.w;
      float kU0d = neUd.x + ((pkUd & 1) ? se1.x : se0.x) + dUd * tbUd.x + tbUd.y;
      float kU1d = neUd.y + ((pkUd & 1) ? se1.y : se0.y) + dUd * tbUd.z + tbUd.w;
      float kV0a = neVa.x + ((pkVa & 1) ? se1.x : se0.x) + dVa * tbVa.x + tbVa.y;
      float kV1a = neVa.y + ((pkVa & 1) ? se1.y : se0.y) + dVa * tbVa.z + tbVa.w;
      float kV0b = neVb.x + ((pkVb & 1) ? se1.x : se0.x) + dVb * tbVb.x + tbVb.y;
      float kV1b = neVb.y + ((pkVb & 1) ? se1.y : se0.y) + dVb * tbVb.z + tbVb.w;
      float kV0c = neVc.x + ((pkVc & 1) ? se1.x : se0.x) + dVc * tbVc.x + tbVc.y;
      float kV1c = neVc.y + ((pkVc & 1) ? se1.y : se0.y) + dVc * tbVc.z + tbVc.w;
      float kV0d = neVd.x + ((pkVd & 1) ? se1.x : se0.x) + dVd * tbVd.x + tbVd.y;
      float kV1d = neVd.y + ((pkVd & 1) ? se1.y : se0.y) + dVd * tbVd.z + tbVd.w;

      // ---- dot partials + 4 independent pairwise reductions
      float p0 = qUx * kU0a + qUy * kU1a;
      float p1 = qUx * kU0b + qUy * kU1b;
      float p2 = qUx * kU0c + qUy * kU1c;
      float p3 = qUx * kU0d + qUy * kU1d;
      float p4 = qVx * kV0a + qVy * kV1a;
      float p5 = qVx * kV0b + qVy * kV1b;
      float p6 = qVx * kV0c + qVy * kV1c;
      float p7 = qVx * kV0d + qVy * kV1d;
      float cU01 = red2(p0, p1, b0sel);
      float cU23 = red2(p2, p3, b0sel);
      float cV01 = red2(p4, p5, b0sel);
      float cV23 = red2(p6, p7, b0sel);

      float sUa = vUa ? (fU ? -1e9f : rdlane<0>(cU01)) : -3.0e38f;
      float sUb = vUb ? (fU ? -1e9f : rdlane<1>(cU01)) : -3.0e38f;
      float sUc = vUc ? (fU ? -1e9f : rdlane<0>(cU23)) : -3.0e38f;
      float sUd = vUd ? (fU ? -1e9f : rdlane<1>(cU23)) : -3.0e38f;
      float sVa = vVa ? (fV ? -1e9f : rdlane<0>(cV01)) : -3.0e38f;
      float sVb = vVb ? (fV ? -1e9f : rdlane<1>(cV01)) : -3.0e38f;
      float sVc = vVc ? (fV ? -1e9f : rdlane<0>(cV23)) : -3.0e38f;
      float sVd = vVd ? (fV ? -1e9f : rdlane<1>(cV23)) : -3.0e38f;

      // ---- 4-wide online-max softmax accumulate (one rescale per side)
      float mnU = fmaxf(fmaxf(mxU, fmaxf(sUa, sUb)), fmaxf(sUc, sUd));
      float alU = __expf(mxU - mnU);
      float wUa = __expf(sUa - mnU), wUb = __expf(sUb - mnU);
      float wUc = __expf(sUc - mnU), wUd = __expf(sUd - mnU);
      ssU = ssU * alU + ((wUa + wUb) + (wUc + wUd));
      zU0 = zU0 * alU + ((wUa * kU0a + wUb * kU0b) + (wUc * kU0c + wUd * kU0d));
      zU1 = zU1 * alU + ((wUa * kU1a + wUb * kU1b) + (wUc * kU1c + wUd * kU1d));
      mxU = mnU;

      float mnV = fmaxf(fmaxf(mxV, fmaxf(sVa, sVb)), fmaxf(sVc, sVd));
      float alV = __expf(mxV - mnV);
      float wVa = __expf(sVa - mnV), wVb = __expf(sVb - mnV);
      float wVc = __expf(sVc - mnV), wVd = __expf(sVd - mnV);
      ssV = ssV * alV + ((wVa + wVb) + (wVc + wVd));
      zV0 = zV0 * alV + ((wVa * kV0a + wVb * kV0b) + (wVc * kV0c + wVd * kV0d));
      zV1 = zV1 * alV + ((wVa * kV1a + wVb * kV1b) + (wVc * kV1c + wVd * kV1d));
      mxV = mnV;
    }
    #undef RANK4

    // unified normalize: fallback sides have ss == 20.0 exactly
    float invU = 1.f / ssU; zU0 *= invU; zU1 *= invU;
    float invV = 1.f / ssV; zV0 *= invV; zV1 *= invV;

    int sw = (e & 7) << 1;
    int ccU = lane ^ sw;
    int ccV = (64 + lane) ^ sw;
    *(float2*)&zbuf[(e << 8) + (ccU << 1)] = make_float2(zU0, zU1);
    *(float2*)&zbuf[(e << 8) + (ccV << 1)] = make_float2(zV0, zV1);
  }
}

// Main fused kernel: 4 waves/block, each wave owns 4 edges (8 sides) with
// dual-side + quad-key ILP, pinned load batching, pairwise reductions.
// bounds(256,4): VGPR cap 128. zu/zv XOR-swizzled in 16 KB LDS;
// MLP layer 1 via split-bf16 MFMA with derived columns built on the fly.
__global__ __launch_bounds__(256, 4) void tgat_main_kernel(
    const int* __restrict__ edge_index, const int* __restrict__ edge_ts,
    const int* __restrict__ hist_nb, const int* __restrict__ hist_tm,
    const int* __restrict__ hist_sg,
    const float* __restrict__ node_emb, const float* __restrict__ sign_emb,
    const float* __restrict__ em_b1,
    const float* __restrict__ em_w2, const float* __restrict__ em_b2,
    const float* __restrict__ ws, float* __restrict__ out, int B)
{
  // zbuf rows = 16 edges, 256 floats (zu|zv) per row, float2-chunk XOR swizzle:
  // logical chunk c of row e stored at chunk c ^ ((e&7)<<1). 16 KB total.
  __shared__ __align__(16) float zbuf[EPB * 256];

  int tid = threadIdx.x;
  int lane = tid & 63;
  int wv = __builtin_amdgcn_readfirstlane(tid >> 6);
  int b0 = blockIdx.x * EPB;

  int M = ((const int*)(ws + WS_CNT))[0];
  float th0 = (lane       < M) ? ws[WS_THM + lane      ] : 3.0e38f;
  float th1 = (lane + 64  < M) ? ws[WS_THM + lane + 64 ] : 3.0e38f;
  float2 se0 = *(const float2*)(sign_emb + 2 * lane);
  float2 se1 = *(const float2*)(sign_emb + H + 2 * lane);

  int sbase = wv * 8;
  if (M <= 128) {
    run_sides<2>(sbase, b0, B, lane, edge_index, edge_ts, hist_nb, hist_tm,
                 hist_sg, node_emb, ws, th0, th1, 3.0e38f, 3.0e38f,
                 se0, se1, zbuf);
  } else {
    float th2 = (lane + 128 < M) ? ws[WS_THM + lane + 128] : 3.0e38f;
    float th3 = (lane + 192 < M) ? ws[WS_THM + lane + 192] : 3.0e38f;
    run_sides<4>(sbase, b0, B, lane, edge_index, edge_ts, hist_nb, hist_tm,
                 hist_sg, node_emb, ws, th0, th1, th2, th3,
                 se0, se1, zbuf);
  }
  __syncthreads();

  // ---- MLP layer 1 via split-bf16 MFMA: hid[16][128] = feat[16][512] @ em_w1
  // feat regions: [zu | zv | |zu-zv| | zu*zv], built on the fly from zbuf.
  const unsigned short* whi = (const unsigned short*)(ws + WSB_HI);
  const unsigned short* wlo = (const unsigned short*)(ws + WSB_LO);
  int c0 = 2 * wv;
  int m_ = lane & 15;
  int qd = lane >> 4;
  int sw = (m_ & 7) << 1;
  const float* zrow = zbuf + (m_ << 8);
  f32x4 acc0 = {0.f, 0.f, 0.f, 0.f};
  f32x4 acc1 = {0.f, 0.f, 0.f, 0.f};
  #pragma unroll
  for (int kc = 0; kc < 16; kc++) {
    const int reg = kc >> 2;
    int cb = (kc & 3) * 16 + qd * 4;     // base chunk within a 128-dim region
    float av[8];
    if (reg == 0) {
      float4 A0 = *(const float4*)(zrow + (((cb    ) ^ sw) << 1));
      float4 A1 = *(const float4*)(zrow + (((cb + 2) ^ sw) << 1));
      av[0]=A0.x; av[1]=A0.y; av[2]=A0.z; av[3]=A0.w;
      av[4]=A1.x; av[5]=A1.y; av[6]=A1.z; av[7]=A1.w;
    } else if (reg == 1) {
      float4 A0 = *(const float4*)(zrow + (((cb + 64) ^ sw) << 1));
      float4 A1 = *(const float4*)(zrow + (((cb + 66) ^ sw) << 1));
      av[0]=A0.x; av[1]=A0.y; av[2]=A0.z; av[3]=A0.w;
      av[4]=A1.x; av[5]=A1.y; av[6]=A1.z; av[7]=A1.w;
    } else {
      float4 U0 = *(const float4*)(zrow + (((cb    ) ^ sw) << 1));
      float4 U1 = *(const float4*)(zrow + (((cb + 2) ^ sw) << 1));
      float4 V0 = *(const float4*)(zrow + (((cb + 64) ^ sw) << 1));
      float4 V1 = *(const float4*)(zrow + (((cb + 66) ^ sw) << 1));
      float uu[8] = {U0.x,U0.y,U0.z,U0.w,U1.x,U1.y,U1.z,U1.w};
      float vvv[8] = {V0.x,V0.y,V0.z,V0.w,V1.x,V1.y,V1.z,V1.w};
      if (reg == 2) {
        #pragma unroll
        for (int j = 0; j < 8; j++) av[j] = fabsf(uu[j] - vvv[j]);
      } else {
        #pragma unroll
        for (int j = 0; j < 8; j++) av[j] = uu[j] * vvv[j];
      }
    }
    // split-bf16 A fragments: hi = bit-truncation (v_perm pack, 1 op/pair),
    // lo = exact residual (Sterbenz) rounded-ne as a packed pair.
    union { short8 v; unsigned u[4]; } ahi, alo;
    #pragma unroll
    for (int j = 0; j < 4; j++) {
      unsigned b0u = __float_as_uint(av[2 * j]);
      unsigned b1u = __float_as_uint(av[2 * j + 1]);
      ahi.u[j] = __builtin_amdgcn_perm(b1u, b0u, 0x07060302u);
      float l0 = av[2 * j]     - __uint_as_float(b0u & 0xFFFF0000u);
      float l1 = av[2 * j + 1] - __uint_as_float(b1u & 0xFFFF0000u);
      __hip_bfloat162 lp = __float22bfloat162_rn(make_float2(l0, l1));
      __builtin_memcpy(&alo.u[j], &lp, 4);
    }
    int f0 = (((c0    ) * 16 + kc) * 64 + lane) * 8;
    int f1 = (((c0 + 1) * 16 + kc) * 64 + lane) * 8;
    short8 bh0 = *(const short8*)(whi + f0);
    short8 bl0 = *(const short8*)(wlo + f0);
    short8 bh1 = *(const short8*)(whi + f1);
    short8 bl1 = *(const short8*)(wlo + f1);
    acc0 = __builtin_amdgcn_mfma_f32_16x16x32_bf16(ahi.v, bh0, acc0, 0, 0, 0);
    acc0 = __builtin_amdgcn_mfma_f32_16x16x32_bf16(ahi.v, bl0, acc0, 0, 0, 0);
    acc0 = __builtin_amdgcn_mfma_f32_16x16x32_bf16(alo.v, bh0, acc0, 0, 0, 0);
    acc1 = __builtin_amdgcn_mfma_f32_16x16x32_bf16(ahi.v, bh1, acc1, 0, 0, 0);
    acc1 = __builtin_amdgcn_mfma_f32_16x16x32_bf16(ahi.v, bl1, acc1, 0, 0, 0);
    acc1 = __builtin_amdgcn_mfma_f32_16x16x32_bf16(alo.v, bh1, acc1, 0, 0, 0);
  }
  __syncthreads();   // all A-reads of zbuf complete before overlay reuse

  // bias + relu, write hid into zbuf overlay (stride 132)
  float* hp = zbuf;
  float eb0 = em_b1[c0 * 16 + m_];
  float eb1 = em_b1[(c0 + 1) * 16 + m_];
  #pragma unroll
  for (int r = 0; r < 4; r++) {
    int edge = qd * 4 + r;
    hp[edge * 132 + c0 * 16 + m_]       = fmaxf(acc0[r] + eb0, 0.f);
    hp[edge * 132 + (c0 + 1) * 16 + m_] = fmaxf(acc1[r] + eb1, 0.f);
  }
  __syncthreads();

  // ---- layer 2: logits = hid @ em_w2 + em_b2 ; wave wv does edges wv*4..+3
  float2 w2v = *(const float2*)(em_w2 + 2 * lane);
  float bias2 = em_b2[0];
  #pragma unroll
  for (int i = 0; i < 4; i++) {
    int e = wv * 4 + i;
    int b = b0 + e;
    float2 hv = *(const float2*)(hp + e * 132 + 2 * lane);
    float p = wave_sum63(hv.x * w2v.x + hv.y * w2v.y);
    float ps = bcast63(p);
    if (lane == 0 && b < B) out[b] = ps + bias2;
  }
}

extern "C" void kernel_launch(void* const* d_in, const int* in_sizes, int n_in,
                              void* d_out, int out_size, void* d_ws, size_t ws_size,
                              hipStream_t stream)
{
  (void)n_in; (void)out_size; (void)ws_size;
  const int* edge_index = (const int*)d_in[0];
  const int* edge_ts    = (const int*)d_in[1];
  const int* hist_nb    = (const int*)d_in[2];
  const int* hist_tm    = (const int*)d_in[3];
  const int* hist_sg    = (const int*)d_in[4];
  const float* node_emb = (const float*)d_in[5];
  const float* sign_emb = (const float*)d_in[6];
  const float* tp_w1    = (const float*)d_in[7];
  const float* tp_b1    = (const float*)d_in[8];
  const float* tp_w2    = (const float*)d_in[9];
  const float* tp_b2    = (const float*)d_in[10];
  const float* em_w1    = (const float*)d_in[11];
  const float* em_b1    = (const float*)d_in[12];
  const float* em_w2    = (const float*)d_in[13];
  const float* em_b2    = (const float*)d_in[14];
  float* out = (float*)d_out;
  float* ws  = (float*)d_ws;
  int B = in_sizes[1];

  hipLaunchKernelGGL(aux_kernel, dim3(769), dim3(128), 0, stream,
                     tp_w1, tp_b1, tp_w2, tp_b2, em_w1, ws);
  int grid = (B + EPB - 1) / EPB;
  hipLaunchKernelGGL(tgat_main_kernel, dim3(grid), dim3(256), 0, stream,
                     edge_index, edge_ts, hist_nb, hist_tm, hist_sg,
                     node_emb, sign_emb, em_b1, em_w2, em_b2, ws, out, B);
}